// Round 1
// baseline (158.595 us; speedup 1.0000x reference)
//
#include <hip/hip_runtime.h>

// Problem constants (from reference)
#define CLASSES   128
#define M_IN      64
#define N_OUT     32
#define N_SAMPLES 65536

// One thread per output element: gid = n*32 + j.
// out[n, j] = dot(x[n, :], W[inds[n]*32 + j, :]) + b[inds[n]*32 + j]
__global__ __launch_bounds__(256) void condmul_kernel(
    const float* __restrict__ x,     // (N_SAMPLES, M_IN)
    const int*   __restrict__ inds,  // (N_SAMPLES,)
    const float* __restrict__ W,     // (CLASSES*N_OUT, M_IN)
    const float* __restrict__ b,     // (CLASSES*N_OUT,)
    float*       __restrict__ out)   // (N_SAMPLES, N_OUT)
{
    const int gid = blockIdx.x * blockDim.x + threadIdx.x;
    const int n = gid >> 5;   // sample index (shared by 32 consecutive lanes)
    const int j = gid & 31;   // output column within the class slice

    const int c   = inds[n];            // broadcast load across the half-wave
    const int row = c * N_OUT + j;

    const float4* __restrict__ xr =
        reinterpret_cast<const float4*>(x + (size_t)n * M_IN);
    const float4* __restrict__ wr =
        reinterpret_cast<const float4*>(W + (size_t)row * M_IN);

    float acc = 0.0f;
#pragma unroll
    for (int k = 0; k < M_IN / 4; ++k) {
        const float4 a = xr[k];   // same-address broadcast within half-wave
        const float4 w = wr[k];   // contiguous per-thread, L2-resident
        acc += a.x * w.x + a.y * w.y + a.z * w.z + a.w * w.w;
    }

    out[gid] = acc + b[row];
}

extern "C" void kernel_launch(void* const* d_in, const int* in_sizes, int n_in,
                              void* d_out, int out_size, void* d_ws, size_t ws_size,
                              hipStream_t stream) {
    const float* x    = (const float*)d_in[0];
    const int*   inds = (const int*)  d_in[1];
    const float* W    = (const float*)d_in[2];
    const float* b    = (const float*)d_in[3];
    float*       out  = (float*)d_out;

    const int total  = N_SAMPLES * N_OUT;       // 2,097,152 threads
    const int block  = 256;
    const int grid   = total / block;           // 8192 blocks

    condmul_kernel<<<grid, block, 0, stream>>>(x, inds, W, b, out);
}

// Round 2
// 94.129 us; speedup vs baseline: 1.6849x; 1.6849x over previous
//
#include <hip/hip_runtime.h>

// Problem constants (from reference)
#define CLASSES   128
#define M_IN      64
#define N_OUT     32
#define N_SAMPLES 65536

// One WAVE (64 lanes) per sample.
//   lane l, step i: loads W-slice float4 #(i*64+l)  -> row r = i*4 + (l>>4), kvec = l&15
//   lane l's x fragment: x4[l&15] (256 B, broadcast within wave)
//   partial p[i] = dot4(w, x4); butterfly-sum over the 16-lane k-group gives row sums.
//   LDS transpose (32 floats/wave) -> coalesced bias add + store.
__global__ __launch_bounds__(256) void condmul_kernel(
    const float* __restrict__ x,     // (N_SAMPLES, M_IN)
    const int*   __restrict__ inds,  // (N_SAMPLES,)
    const float* __restrict__ W,     // (CLASSES*N_OUT, M_IN)
    const float* __restrict__ b,     // (CLASSES*N_OUT,)
    float*       __restrict__ out)   // (N_SAMPLES, N_OUT)
{
    const int waveInBlock = threadIdx.x >> 6;
    const int lane        = threadIdx.x & 63;
    const int n           = (blockIdx.x << 2) + waveInBlock;   // sample index

    const int m = lane & 15;   // k-chunk (float4 index into x row)
    const int q = lane >> 4;   // row-group (row % 4)

    // class index — wave-uniform; force scalar so W addressing is SGPR-based
    const int c = __builtin_amdgcn_readfirstlane(inds[n]);

    const float4* __restrict__ Wb =
        reinterpret_cast<const float4*>(W + (size_t)c * (N_OUT * M_IN)); // 512 float4
    const float4 xv =
        reinterpret_cast<const float4*>(x + (size_t)n * M_IN)[m];

    float p[8];
#pragma unroll
    for (int i = 0; i < 8; ++i) {
        const float4 w = Wb[i * 64 + lane];      // fully coalesced 1 KB/instruction
        p[i] = w.x * xv.x + w.y * xv.y + w.z * xv.z + w.w * xv.w;
    }

    // Sum each partial across its 16-lane k-group (xor masks 1,2,4,8 stay in-group)
#pragma unroll
    for (int i = 0; i < 8; ++i) {
#pragma unroll
        for (int off = 8; off >= 1; off >>= 1) {
            p[i] += __shfl_xor(p[i], off, 64);
        }
    }

    // Transpose through LDS: lane with m==0 in each row-group q holds rows {i*4+q}
    __shared__ float lds[4 * N_OUT];             // 32 floats per wave
    float* slot = lds + (waveInBlock << 5);
    if (m == 0) {
#pragma unroll
        for (int i = 0; i < 8; ++i) {
            slot[i * 4 + q] = p[i];              // static register indices
        }
    }
    __syncthreads();

    if (lane < N_OUT) {
        const float v = slot[lane] + b[c * N_OUT + lane];   // coalesced bias read
        out[(size_t)n * N_OUT + lane] = v;                  // coalesced 128 B store
    }
}

extern "C" void kernel_launch(void* const* d_in, const int* in_sizes, int n_in,
                              void* d_out, int out_size, void* d_ws, size_t ws_size,
                              hipStream_t stream) {
    const float* x    = (const float*)d_in[0];
    const int*   inds = (const int*)  d_in[1];
    const float* W    = (const float*)d_in[2];
    const float* b    = (const float*)d_in[3];
    float*       out  = (float*)d_out;

    const int block = 256;                       // 4 waves/block, 1 sample/wave
    const int grid  = N_SAMPLES / 4;             // 16384 blocks

    condmul_kernel<<<grid, block, 0, stream>>>(x, inds, W, b, out);
}